// Round 13
// baseline (258.400 us; speedup 1.0000x reference)
//
#include <hip/hip_runtime.h>
#include <hip/hip_fp16.h>

// Problem constants: B=16, N=128, H=128, BD=64, P=256
using f16x4 = __attribute__((ext_vector_type(4))) _Float16;
using f16x8 = __attribute__((ext_vector_type(8))) _Float16;
using f32x4 = __attribute__((ext_vector_type(4))) float;

__device__ __forceinline__ f16x4 ld_f16x4(const void* p) {
    return *reinterpret_cast<const f16x4*>(p);
}
__device__ __forceinline__ f16x8 ld_f16x8(const void* p) {
    return *reinterpret_cast<const f16x8*>(p);
}

// ---------------------------------------------------------------------------
// k-slot convention (consistent across BOTH MFMA operands => contraction is
// exact for any bijection): for K=32 f16 MFMA, lane group lk (lane>>4),
// register element e (0..7) holds k-slot (lk, e).
//  GEMM1 labeling: k = s32*32 + lk*8 + e          (plain, W2bt = plain transpose)
//  GEMM2 labeling: k = ks*32 + sigma(lk,e), sigma = (e>>2)*16 + 4*lk + (e&3)
//   (matches GEMM1's C/D quad packing of u, so u needs NO shuffles).
//
// Prep kernel A: W2bt[p][k] = W2[128+k][p] (f16 plain transpose, 64/row).
//  W3 -> W3s: [ks][row p'][4 slots x 8 f16]; slot s at row holds k-group
//  g = s ^ ((row>>1)&3) (read-side bank swizzle folded in), element e ->
//  k = ks*32 + sigma(g,e).
//  T1h[b*128+n][64] = pos[b,n]@W1 (f16, NO b1) -- enc(i,j) = relu(T1[j]+b1-T1[i])
// ---------------------------------------------------------------------------
__global__ void sp_wconv(const float* __restrict__ W2, const float* __restrict__ W3,
                         const float* __restrict__ pos, const float* __restrict__ W1,
                         _Float16* __restrict__ W2bt, _Float16* __restrict__ W3s,
                         _Float16* __restrict__ T1h) {
    int t = blockIdx.x * 256 + threadIdx.x;   // grid covers 65536
    if (t < 16384) {
        int p = t >> 6, k = t & 63;
        W2bt[t] = (_Float16)W2[(128 + k) * 256 + p];
    }
    {
        int ks = t >> 13, rem = t & 8191;
        int row = rem >> 5, inner = rem & 31;
        int slot = inner >> 3, e = inner & 7;
        int g = slot ^ ((row >> 1) & 3);
        int k = ks * 32 + ((e & 4) << 2) + (g << 2) + (e & 3);
        W3s[t] = (_Float16)W3[k * 256 + row];
    }
#pragma unroll
    for (int h = 0; h < 2; ++h) {
        int idx = t + h * 65536;              // 131072 = 2048 rows x 64
        int row = idx >> 6, k = idx & 63;
        T1h[idx] = (_Float16)(pos[row * 2] * W1[k] + pos[row * 2 + 1] * W1[64 + k]);
    }
}

// ---------------------------------------------------------------------------
// Prep kernel B: hp16[b*128+j][p] = hid[b,j,:] @ W2[0:128,p] + b2[p]  (f16)
// ---------------------------------------------------------------------------
__global__ void sp_hpart(const float* __restrict__ hs, const float* __restrict__ W2,
                         const float* __restrict__ b2, _Float16* __restrict__ hp16) {
    __shared__ float sh[8 * 128];
    int rb = blockIdx.x * 8;
    int tid = threadIdx.x;
    for (int t = tid; t < 1024; t += 256) sh[t] = hs[rb * 128 + t];
    __syncthreads();
    float acc[8];
    float bb = b2[tid];
#pragma unroll
    for (int r = 0; r < 8; ++r) acc[r] = bb;
    for (int k = 0; k < 128; ++k) {
        float w = W2[k * 256 + tid];
#pragma unroll
        for (int r = 0; r < 8; ++r) acc[r] += sh[r * 128 + k] * w;
    }
#pragma unroll
    for (int r = 0; r < 8; ++r) hp16[(rb + r) * 256 + tid] = (_Float16)acc[r];
}

// ---------------------------------------------------------------------------
// Main kernel: one block per (b, ph-quarter, i-group of 8) -> grid 1024.
// 4 waves; wave wj owns j in [32wj, 32wj+32). TARGET: 4 blocks/CU (16
// waves/CU = 4/SIMD) via 36KB LDS + <=128 unified regs/wave.
//  Register plan (r10-r12 lessons): GEMM1 fused into GEMM2 per-ks so the
//  u A-frags live 8 regs (not 64); eacc[2][4]=32; aprime (T1[j]+b1) cached
//  16 regs; full unrolls (static idx); opaque ptrs block LICM of the
//  i-invariant w2p/hpp loads.
//  Per i (barrier-free, sW3q read-only): benc = relu(aprime - T1[i]) ->
//  per ks { GEMM1 2pt -> u jit -> GEMM2 4pt' } -> masked max -> sPoolH.
// LDS: 8x4KB W3 quarter + 4KB pool = 36KB. Grid 16b x 4ph x 16ig.
// ---------------------------------------------------------------------------
__global__ __launch_bounds__(256, 4) void sp_main(
    const float* __restrict__ b1, const float* __restrict__ b3,
    const _Float16* __restrict__ hp16, const _Float16* __restrict__ W2bt,
    const _Float16* __restrict__ W3s, const _Float16* __restrict__ T1h,
    float* __restrict__ pool) {
    __shared__ __align__(16) char sW3q[8][4096];   // [ks][64 rows local][64B]
    __shared__ _Float16 sPoolH[4][8][64];          // [wj][ii][p'-local]

    const int bid = blockIdx.x;
    const int ig = bid & 15, ph = (bid >> 4) & 3, b = bid >> 6;
    const int tid = threadIdx.x;
    const int wj = tid >> 6, lane = tid & 63;
    const int l15 = lane & 15, lk = lane >> 4;

    // --- stage W3 quarter (32KB): rows [ph*64, ph*64+64) of each ks chunk --
    {
        const uint4* W3v = (const uint4*)W3s;
        uint4* dst = (uint4*)sW3q;
#pragma unroll
        for (int c = 0; c < 8; ++c)
            dst[c * 256 + tid] = W3v[c * 1024 + ph * 256 + tid];
    }

    // --- aprime[jt][s32] = f16(T1[j] + b1)  (i-invariant, 16 regs) ---------
    f16x8 aprime[2][2];
#pragma unroll
    for (int jt = 0; jt < 2; ++jt) {
        int j = wj * 32 + jt * 16 + l15;
        const _Float16* tj = T1h + (b * 128 + j) * 64 + lk * 8;
#pragma unroll
        for (int s32 = 0; s32 < 2; ++s32) {
            f16x8 tv = ld_f16x8(tj + s32 * 32);
            f32x4 b0 = *(const f32x4*)(b1 + s32 * 32 + lk * 8);
            f32x4 b4 = *(const f32x4*)(b1 + s32 * 32 + lk * 8 + 4);
            f16x8 v;
#pragma unroll
            for (int e = 0; e < 4; ++e) {
                v[e]     = (_Float16)((float)tv[e]     + b0[e]);
                v[e + 4] = (_Float16)((float)tv[e + 4] + b4[e]);
            }
            aprime[jt][s32] = v;
        }
    }

    const _Float16* hpb = hp16 + (b * 128 + wj * 32 + l15) * 256 + lk * 4;
    const _Float16* tib = T1h + (b * 128) * 64 + lk * 8;   // + i*64 per iter
    const int slot = lk ^ ((l15 >> 1) & 3);   // read-side bank swizzle

    __syncthreads();   // sW3q ready

    // ======================= barrier-free i-loop ===========================
#pragma unroll 1
    for (int ii = 0; ii < 8; ++ii) {
        const int i = ig * 8 + ii;

        // Opaque passthroughs: block LICM from hoisting i-invariant loads.
        const _Float16* w2p = W2bt;
        const _Float16* hpp = hpb;
        asm volatile("" : "+v"(w2p), "+v"(hpp));

        // --- benc = relu(aprime - T1[i])  (packed f16) ----------------------
        f16x8 benc[2][2];
#pragma unroll
        for (int s32 = 0; s32 < 2; ++s32) {
            f16x8 cv = ld_f16x8(tib + i * 64 + s32 * 32);
#pragma unroll
            for (int jt = 0; jt < 2; ++jt) {
                f16x8 v;
#pragma unroll
                for (int e = 0; e < 8; ++e) {
                    _Float16 d = aprime[jt][s32][e] - cv[e];
                    v[e] = d > (_Float16)0 ? d : (_Float16)0;
                }
                benc[jt][s32] = v;
            }
        }

        f32x4 eacc[2][4];
#pragma unroll
        for (int jt = 0; jt < 2; ++jt)
#pragma unroll
            for (int pt = 0; pt < 4; ++pt) eacc[jt][pt] = (f32x4){0.f, 0.f, 0.f, 0.f};

        // --- fused per-ks: GEMM1 (2 pt) -> u jit -> GEMM2 (4 pt') -----------
#pragma unroll
        for (int ks = 0; ks < 8; ++ks) {
            f16x8 u0, u1;
#pragma unroll
            for (int pp = 0; pp < 2; ++pp) {
                const int pt = ks * 2 + pp;
                f32x4 a0 = (f32x4){0.f, 0.f, 0.f, 0.f};
                f32x4 a1 = (f32x4){0.f, 0.f, 0.f, 0.f};
#pragma unroll
                for (int s32 = 0; s32 < 2; ++s32) {
                    f16x8 aw = ld_f16x8(w2p + (pt * 16 + l15) * 64 + s32 * 32 + lk * 8);
                    a0 = __builtin_amdgcn_mfma_f32_16x16x32_f16(aw, benc[0][s32], a0, 0, 0, 0);
                    a1 = __builtin_amdgcn_mfma_f32_16x16x32_f16(aw, benc[1][s32], a1, 0, 0, 0);
                }
                f16x4 h0 = ld_f16x4(hpp + pt * 16);
                f16x4 h1 = ld_f16x4(hpp + 16 * 256 + pt * 16);
#pragma unroll
                for (int r = 0; r < 4; ++r) {
                    float t0 = a0[r] + (float)h0[r];
                    float t1 = a1[r] + (float)h1[r];
                    u0[pp * 4 + r] = (_Float16)(t0 > 0.f ? t0 : 0.f);
                    u1[pp * 4 + r] = (_Float16)(t1 > 0.f ? t1 : 0.f);
                }
            }
#pragma unroll
            for (int pt = 0; pt < 4; ++pt) {
                f16x8 bf = ld_f16x8(sW3q[ks] + (pt * 16 + l15) * 64 + slot * 16);
                eacc[0][pt] = __builtin_amdgcn_mfma_f32_16x16x32_f16(u0, bf, eacc[0][pt], 0, 0, 0);
                eacc[1][pt] = __builtin_amdgcn_mfma_f32_16x16x32_f16(u1, bf, eacc[1][pt], 0, 0, 0);
            }
        }

        // --- masked max over this wave's 32 j -> private sPoolH slice ------
        // eacc: row j = wj*32 + jt*16 + 4lk + r, col p' = ph*64 + pt*16 + l15
#pragma unroll
        for (int pt = 0; pt < 4; ++pt) {
            float m = -INFINITY;
#pragma unroll
            for (int jt = 0; jt < 2; ++jt) {
#pragma unroll
                for (int r = 0; r < 4; ++r) {
                    int row = wj * 32 + jt * 16 + lk * 4 + r;
                    float v = eacc[jt][pt][r];
                    if (row != i) m = fmaxf(m, v);
                }
            }
            m = fmaxf(m, __shfl_xor(m, 16));
            m = fmaxf(m, __shfl_xor(m, 32));
            if (lane < 16) sPoolH[wj][ii][pt * 16 + l15] = (_Float16)m;
        }
    }
    __syncthreads();   // all waves' sPoolH complete

    // --- cross-wave max + b3 -> pooled rows (d_out, write-only) ------------
#pragma unroll
    for (int q = 0; q < 2; ++q) {
        int idx = q * 256 + tid;           // 0..511 = 8 ii x 64 p'-local
        int ii = idx >> 6, t = idx & 63;
        float v = fmaxf(fmaxf((float)sPoolH[0][ii][t], (float)sPoolH[1][ii][t]),
                        fmaxf((float)sPoolH[2][ii][t], (float)sPoolH[3][ii][t]));
        int p = ph * 64 + t;
        pool[(b * 128 + ig * 8 + ii) * 256 + p] = v + b3[p];
    }
}

// ---------------------------------------------------------------------------
// Final: io = io @ Wout + bout, IN PLACE on d_out (8 rows per block; rows
// staged to LDS behind a barrier before any write -> in-place safe).
// ---------------------------------------------------------------------------
__global__ void sp_out(const float* __restrict__ Wout, const float* __restrict__ bout,
                       float* __restrict__ io) {
    __shared__ float sp[8 * 256];
    int rb = blockIdx.x * 8;
    int tid = threadIdx.x;
    for (int t = tid; t < 2048; t += 256) sp[t] = io[rb * 256 + t];
    __syncthreads();
    float acc[8];
    float bb = bout[tid];
#pragma unroll
    for (int r = 0; r < 8; ++r) acc[r] = bb;
    for (int k = 0; k < 256; ++k) {
        float w = Wout[k * 256 + tid];
#pragma unroll
        for (int r = 0; r < 8; ++r) acc[r] += sp[r * 256 + k] * w;
    }
#pragma unroll
    for (int r = 0; r < 8; ++r) io[(rb + r) * 256 + tid] = acc[r];
}

extern "C" void kernel_launch(void* const* d_in, const int* in_sizes, int n_in,
                              void* d_out, int out_size, void* d_ws, size_t ws_size,
                              hipStream_t stream) {
    const float* hs   = (const float*)d_in[0];
    const float* pos  = (const float*)d_in[1];
    const float* W1   = (const float*)d_in[2];
    const float* b1   = (const float*)d_in[3];
    const float* W2   = (const float*)d_in[4];
    const float* b2   = (const float*)d_in[5];
    const float* W3   = (const float*)d_in[6];
    const float* b3   = (const float*)d_in[7];
    const float* Wout = (const float*)d_in[8];
    const float* bout = (const float*)d_in[9];
    float* out = (float*)d_out;

    // ws layout: hp16 1MB | W2bt 32KB | W3s 128KB | T1h 256KB (~1.4MB total)
    _Float16* hp16 = (_Float16*)d_ws;
    _Float16* W2bt = (_Float16*)((char*)d_ws + (1 << 20));
    _Float16* W3s  = (_Float16*)((char*)d_ws + (1 << 20) + 32768);
    _Float16* T1h  = (_Float16*)((char*)d_ws + (1 << 20) + 32768 + 131072);

    sp_wconv<<<256, 256, 0, stream>>>(W2, W3, pos, W1, W2bt, W3s, T1h);
    sp_hpart<<<256, 256, 0, stream>>>(hs, W2, b2, hp16);
    sp_main<<<1024, 256, 0, stream>>>(b1, b3, hp16, W2bt, W3s, T1h, out);
    sp_out<<<256, 256, 0, stream>>>(Wout, bout, out);
}

// Round 14
// 123.283 us; speedup vs baseline: 2.0960x; 2.0960x over previous
//
#include <hip/hip_runtime.h>
#include <hip/hip_fp16.h>

// Problem constants: B=16, N=128, H=128, BD=64, P=256
using f16x4 = __attribute__((ext_vector_type(4))) _Float16;
using f16x8 = __attribute__((ext_vector_type(8))) _Float16;
using f32x4 = __attribute__((ext_vector_type(4))) float;

__device__ __forceinline__ f16x4 ld_f16x4(const void* p) {
    return *reinterpret_cast<const f16x4*>(p);
}
__device__ __forceinline__ f16x8 ld_f16x8(const void* p) {
    return *reinterpret_cast<const f16x8*>(p);
}

// ---------------------------------------------------------------------------
// k-slot convention (consistent across BOTH MFMA operands => contraction is
// exact for any bijection): for K=32 f16 MFMA, lane group lk (lane>>4),
// register element e (0..7) holds k-slot (lk, e).
//  GEMM1 labeling: k = s32*32 + lk*8 + e          (plain, W2bt = plain transpose)
//  GEMM2 labeling: k = ks*32 + sigma(lk,e), sigma = (e>>2)*16 + 4*lk + (e&3)
//   (matches GEMM1's C/D quad packing of u, so u needs NO shuffles).
//
// Prep kernel A: W2bt[p][k] = W2[128+k][p] (f16 plain transpose, 64/row).
//  W3 -> W3s: [ks][row p'][4 slots x 8 f16]; slot s at row holds k-group
//  g = s ^ ((row>>1)&3) (read-side bank swizzle folded in), element e ->
//  k = ks*32 + sigma(g,e).
//  T1h[b*128+n][64] = pos[b,n]@W1 (f16, NO b1) -- enc(i,j) = relu(T1[j]+b1-T1[i])
// ---------------------------------------------------------------------------
__global__ void sp_wconv(const float* __restrict__ W2, const float* __restrict__ W3,
                         const float* __restrict__ pos, const float* __restrict__ W1,
                         _Float16* __restrict__ W2bt, _Float16* __restrict__ W3s,
                         _Float16* __restrict__ T1h) {
    int t = blockIdx.x * 256 + threadIdx.x;   // grid covers 65536
    if (t < 16384) {
        int p = t >> 6, k = t & 63;
        W2bt[t] = (_Float16)W2[(128 + k) * 256 + p];
    }
    {
        int ks = t >> 13, rem = t & 8191;
        int row = rem >> 5, inner = rem & 31;
        int slot = inner >> 3, e = inner & 7;
        int g = slot ^ ((row >> 1) & 3);
        int k = ks * 32 + ((e & 4) << 2) + (g << 2) + (e & 3);
        W3s[t] = (_Float16)W3[k * 256 + row];
    }
#pragma unroll
    for (int h = 0; h < 2; ++h) {
        int idx = t + h * 65536;              // 131072 = 2048 rows x 64
        int row = idx >> 6, k = idx & 63;
        T1h[idx] = (_Float16)(pos[row * 2] * W1[k] + pos[row * 2 + 1] * W1[64 + k]);
    }
}

// ---------------------------------------------------------------------------
// Prep kernel B: hp16[b*128+j][p] = hid[b,j,:] @ W2[0:128,p] + b2[p]  (f16)
// ---------------------------------------------------------------------------
__global__ void sp_hpart(const float* __restrict__ hs, const float* __restrict__ W2,
                         const float* __restrict__ b2, _Float16* __restrict__ hp16) {
    __shared__ float sh[8 * 128];
    int rb = blockIdx.x * 8;
    int tid = threadIdx.x;
    for (int t = tid; t < 1024; t += 256) sh[t] = hs[rb * 128 + t];
    __syncthreads();
    float acc[8];
    float bb = b2[tid];
#pragma unroll
    for (int r = 0; r < 8; ++r) acc[r] = bb;
    for (int k = 0; k < 128; ++k) {
        float w = W2[k * 256 + tid];
#pragma unroll
        for (int r = 0; r < 8; ++r) acc[r] += sh[r * 128 + k] * w;
    }
#pragma unroll
    for (int r = 0; r < 8; ++r) hp16[(rb + r) * 256 + tid] = (_Float16)acc[r];
}

// ---------------------------------------------------------------------------
// Main kernel: one block per (b, ph-half, i-group of 8) -> grid 512
// (2 blocks/CU). 4 waves; wave wj owns j in [32wj, 32wj+32).
//  r12 frame (best: 137us) + redundant-load elimination:
//   - hp persistent: h0/h1 (32 VGPR) loaded ONCE (was 32 loads/i);
//   - T1 table + aprime cached (was 12 W1/b1 loads + ~100 VALU per i);
//   - GEMM1 fused per-ks into GEMM2 (u lives 8 regs, not 64) so the above
//     fits ~188 unified regs at (256,2) with no spill;
//   - only aw (W2bt) loads stay per-i behind an anti-LICM passthrough
//     (caching them = 128 regs = r10's spill).
//  Per i (barrier-free, sW3 read-only): benc = relu(aprime - T1[i]) ->
//  per ks { GEMM1 2pt -> u jit -> GEMM2 8pt' } -> masked max -> sPoolH.
// LDS: 64KB W3-half + 8KB pool = 72KB -> 2 blocks/CU.
// ---------------------------------------------------------------------------
__global__ __launch_bounds__(256, 2) void sp_main(
    const float* __restrict__ b1, const float* __restrict__ b3,
    const _Float16* __restrict__ hp16, const _Float16* __restrict__ W2bt,
    const _Float16* __restrict__ W3s, const _Float16* __restrict__ T1h,
    float* __restrict__ pool) {
    __shared__ __align__(16) char sW3[8][8192];    // [ks][row'-local 128][64B]
    __shared__ _Float16 sPoolH[4][8][128];         // [wj][ii][p'-local]

    const int bid = blockIdx.x;
    const int ig = bid & 15, ph = (bid >> 4) & 1, b = bid >> 5;
    const int tid = threadIdx.x;
    const int wj = tid >> 6, lane = tid & 63;
    const int l15 = lane & 15, lk = lane >> 4;

    // --- stage W3 half (64KB): rows [ph*128, ph*128+128) of each ks chunk --
    {
        const uint4* W3v = (const uint4*)W3s + ph * 512;
        uint4* dst = (uint4*)sW3;
#pragma unroll
        for (int c = 0; c < 16; ++c) {
            dst[c * 256 + tid] = W3v[c * 256 + tid + (c >> 1) * 512];
        }
    }

    // --- aprime[jt][s32] = f16(T1[j] + b1)  (i-invariant, 16 regs) ---------
    f16x8 aprime[2][2];
#pragma unroll
    for (int jt = 0; jt < 2; ++jt) {
        int j = wj * 32 + jt * 16 + l15;
        const _Float16* tj = T1h + (b * 128 + j) * 64 + lk * 8;
#pragma unroll
        for (int s32 = 0; s32 < 2; ++s32) {
            f16x8 tv = ld_f16x8(tj + s32 * 32);
            f32x4 b0 = *(const f32x4*)(b1 + s32 * 32 + lk * 8);
            f32x4 b4 = *(const f32x4*)(b1 + s32 * 32 + lk * 8 + 4);
            f16x8 v;
#pragma unroll
            for (int e = 0; e < 4; ++e) {
                v[e]     = (_Float16)((float)tv[e]     + b0[e]);
                v[e + 4] = (_Float16)((float)tv[e + 4] + b4[e]);
            }
            aprime[jt][s32] = v;
        }
    }

    // --- hp persistent: this lane's 2 j-rows, all 16 pt (32 VGPR, once) ----
    const _Float16* hpb = hp16 + (b * 128 + wj * 32 + l15) * 256 + lk * 4;
    f16x4 h0[16], h1[16];
#pragma unroll
    for (int pt = 0; pt < 16; ++pt) {
        h0[pt] = ld_f16x4(hpb + pt * 16);
        h1[pt] = ld_f16x4(hpb + 16 * 256 + pt * 16);
    }

    const _Float16* tib = T1h + (b * 128) * 64 + lk * 8;   // + i*64 per iter
    const int slot = lk ^ ((l15 >> 1) & 3);   // read-side bank swizzle

    __syncthreads();   // sW3 ready

    // ======================= barrier-free i-loop ===========================
#pragma unroll 1
    for (int ii = 0; ii < 8; ++ii) {
        const int i = ig * 8 + ii;

        // Opaque passthrough: block LICM from hoisting the 32 aw loads
        // (i-invariant but 128 regs if cached -> r10's spill).
        const _Float16* w2p = W2bt;
        asm volatile("" : "+v"(w2p));

        // --- benc = relu(aprime - T1[i])  (packed f16) ----------------------
        f16x8 benc[2][2];
#pragma unroll
        for (int s32 = 0; s32 < 2; ++s32) {
            f16x8 cv = ld_f16x8(tib + i * 64 + s32 * 32);
#pragma unroll
            for (int jt = 0; jt < 2; ++jt) {
                f16x8 v;
#pragma unroll
                for (int e = 0; e < 8; ++e) {
                    _Float16 d = aprime[jt][s32][e] - cv[e];
                    v[e] = d > (_Float16)0 ? d : (_Float16)0;
                }
                benc[jt][s32] = v;
            }
        }

        f32x4 eacc[2][8];
#pragma unroll
        for (int jt = 0; jt < 2; ++jt)
#pragma unroll
            for (int pt = 0; pt < 8; ++pt) eacc[jt][pt] = (f32x4){0.f, 0.f, 0.f, 0.f};

        // --- fused per-ks: GEMM1 (2 pt) -> u jit -> GEMM2 (8 pt') -----------
#pragma unroll
        for (int ks = 0; ks < 8; ++ks) {
            f16x8 u0, u1;
#pragma unroll
            for (int pp = 0; pp < 2; ++pp) {
                const int pt = ks * 2 + pp;
                f32x4 a0 = (f32x4){0.f, 0.f, 0.f, 0.f};
                f32x4 a1 = (f32x4){0.f, 0.f, 0.f, 0.f};
#pragma unroll
                for (int s32 = 0; s32 < 2; ++s32) {
                    f16x8 aw = ld_f16x8(w2p + (pt * 16 + l15) * 64 + s32 * 32 + lk * 8);
                    a0 = __builtin_amdgcn_mfma_f32_16x16x32_f16(aw, benc[0][s32], a0, 0, 0, 0);
                    a1 = __builtin_amdgcn_mfma_f32_16x16x32_f16(aw, benc[1][s32], a1, 0, 0, 0);
                }
#pragma unroll
                for (int r = 0; r < 4; ++r) {
                    float t0 = a0[r] + (float)h0[pt][r];
                    float t1 = a1[r] + (float)h1[pt][r];
                    u0[pp * 4 + r] = (_Float16)(t0 > 0.f ? t0 : 0.f);
                    u1[pp * 4 + r] = (_Float16)(t1 > 0.f ? t1 : 0.f);
                }
            }
#pragma unroll
            for (int pt = 0; pt < 8; ++pt) {
                f16x8 bf = ld_f16x8(sW3[ks] + (pt * 16 + l15) * 64 + slot * 16);
                eacc[0][pt] = __builtin_amdgcn_mfma_f32_16x16x32_f16(u0, bf, eacc[0][pt], 0, 0, 0);
                eacc[1][pt] = __builtin_amdgcn_mfma_f32_16x16x32_f16(u1, bf, eacc[1][pt], 0, 0, 0);
            }
        }

        // --- masked max over this wave's 32 j -> private sPoolH slice ------
        // eacc: row j = wj*32 + jt*16 + 4lk + r, col p' = ph*128 + pt*16 + l15
#pragma unroll
        for (int pt = 0; pt < 8; ++pt) {
            float m = -INFINITY;
#pragma unroll
            for (int jt = 0; jt < 2; ++jt) {
#pragma unroll
                for (int r = 0; r < 4; ++r) {
                    int row = wj * 32 + jt * 16 + lk * 4 + r;
                    float v = eacc[jt][pt][r];
                    if (row != i) m = fmaxf(m, v);
                }
            }
            m = fmaxf(m, __shfl_xor(m, 16));
            m = fmaxf(m, __shfl_xor(m, 32));
            if (lane < 16) sPoolH[wj][ii][pt * 16 + l15] = (_Float16)m;
        }
    }
    __syncthreads();   // all waves' sPoolH complete

    // --- cross-wave max + b3 -> pooled rows (d_out, write-only) ------------
#pragma unroll
    for (int q = 0; q < 4; ++q) {
        int idx = q * 256 + tid;           // 0..1023 = 8 ii x 128 p'-local
        int ii = idx >> 7, t = idx & 127;
        float v = fmaxf(fmaxf((float)sPoolH[0][ii][t], (float)sPoolH[1][ii][t]),
                        fmaxf((float)sPoolH[2][ii][t], (float)sPoolH[3][ii][t]));
        int p = ph * 128 + t;
        pool[(b * 128 + ig * 8 + ii) * 256 + p] = v + b3[p];
    }
}

// ---------------------------------------------------------------------------
// Final: io = io @ Wout + bout, IN PLACE on d_out (8 rows per block; rows
// staged to LDS behind a barrier before any write -> in-place safe).
// ---------------------------------------------------------------------------
__global__ void sp_out(const float* __restrict__ Wout, const float* __restrict__ bout,
                       float* __restrict__ io) {
    __shared__ float sp[8 * 256];
    int rb = blockIdx.x * 8;
    int tid = threadIdx.x;
    for (int t = tid; t < 2048; t += 256) sp[t] = io[rb * 256 + t];
    __syncthreads();
    float acc[8];
    float bb = bout[tid];
#pragma unroll
    for (int r = 0; r < 8; ++r) acc[r] = bb;
    for (int k = 0; k < 256; ++k) {
        float w = Wout[k * 256 + tid];
#pragma unroll
        for (int r = 0; r < 8; ++r) acc[r] += sp[r * 256 + k] * w;
    }
#pragma unroll
    for (int r = 0; r < 8; ++r) io[(rb + r) * 256 + tid] = acc[r];
}

extern "C" void kernel_launch(void* const* d_in, const int* in_sizes, int n_in,
                              void* d_out, int out_size, void* d_ws, size_t ws_size,
                              hipStream_t stream) {
    const float* hs   = (const float*)d_in[0];
    const float* pos  = (const float*)d_in[1];
    const float* W1   = (const float*)d_in[2];
    const float* b1   = (const float*)d_in[3];
    const float* W2   = (const float*)d_in[4];
    const float* b2   = (const float*)d_in[5];
    const float* W3   = (const float*)d_in[6];
    const float* b3   = (const float*)d_in[7];
    const float* Wout = (const float*)d_in[8];
    const float* bout = (const float*)d_in[9];
    float* out = (float*)d_out;

    // ws layout: hp16 1MB | W2bt 32KB | W3s 128KB | T1h 256KB (~1.4MB total)
    _Float16* hp16 = (_Float16*)d_ws;
    _Float16* W2bt = (_Float16*)((char*)d_ws + (1 << 20));
    _Float16* W3s  = (_Float16*)((char*)d_ws + (1 << 20) + 32768);
    _Float16* T1h  = (_Float16*)((char*)d_ws + (1 << 20) + 32768 + 131072);

    sp_wconv<<<256, 256, 0, stream>>>(W2, W3, pos, W1, W2bt, W3s, T1h);
    sp_hpart<<<256, 256, 0, stream>>>(hs, W2, b2, hp16);
    sp_main<<<512, 256, 0, stream>>>(b1, b3, hp16, W2bt, W3s, T1h, out);
    sp_out<<<256, 256, 0, stream>>>(Wout, bout, out);
}

// Round 15
// 99.735 us; speedup vs baseline: 2.5909x; 1.2361x over previous
//
#include <hip/hip_runtime.h>
#include <hip/hip_fp16.h>

// Problem constants: B=16, N=128, H=128, BD=64, P=256
using f16x4 = __attribute__((ext_vector_type(4))) _Float16;
using f16x8 = __attribute__((ext_vector_type(8))) _Float16;
using f32x4 = __attribute__((ext_vector_type(4))) float;

__device__ __forceinline__ f16x4 ld_f16x4(const void* p) {
    return *reinterpret_cast<const f16x4*>(p);
}
__device__ __forceinline__ f16x8 ld_f16x8(const void* p) {
    return *reinterpret_cast<const f16x8*>(p);
}

// ---------------------------------------------------------------------------
// k-slot convention (consistent across BOTH MFMA operands => contraction is
// exact for any bijection): for K=32 f16 MFMA, lane group lk (lane>>4),
// register element e (0..7) holds k-slot (lk, e).
//  GEMM1 labeling: k = s32*32 + lk*8 + e          (plain, W2bt = plain transpose)
//  GEMM2 labeling: k = ks*32 + sigma(lk,e), sigma = (e>>2)*16 + 4*lk + (e&3)
//   (matches GEMM1's C/D quad packing of u, so u needs NO shuffles).
//
// Prep kernel A: W2bt[p][k] = W2[128+k][p] (f16 plain transpose, 64/row).
//  W3 -> W3s: [ks][row p'][4 slots x 8 f16]; slot s at row holds k-group
//  g = s ^ ((row>>1)&3), element e -> k = ks*32 + sigma(g,e).
//  T1h [b*128+n][64] = pos[b,n]@W1        (f16, no bias; used for the i term)
//  T1bh[b*128+n][64] = pos[b,n]@W1 + b1   (f16, bias folded; used for j term)
//  enc(i,j) = relu(T1bh[j] - T1h[i]).
// ---------------------------------------------------------------------------
__global__ void sp_wconv(const float* __restrict__ W2, const float* __restrict__ W3,
                         const float* __restrict__ pos, const float* __restrict__ W1,
                         const float* __restrict__ b1,
                         _Float16* __restrict__ W2bt, _Float16* __restrict__ W3s,
                         _Float16* __restrict__ T1h, _Float16* __restrict__ T1bh) {
    int t = blockIdx.x * 256 + threadIdx.x;   // grid covers 65536
    if (t < 16384) {
        int p = t >> 6, k = t & 63;
        W2bt[t] = (_Float16)W2[(128 + k) * 256 + p];
    }
    {
        int ks = t >> 13, rem = t & 8191;
        int row = rem >> 5, inner = rem & 31;
        int slot = inner >> 3, e = inner & 7;
        int g = slot ^ ((row >> 1) & 3);
        int k = ks * 32 + ((e & 4) << 2) + (g << 2) + (e & 3);
        W3s[t] = (_Float16)W3[k * 256 + row];
    }
#pragma unroll
    for (int h = 0; h < 2; ++h) {
        int idx = t + h * 65536;              // 131072 = 2048 rows x 64
        int row = idx >> 6, k = idx & 63;
        float v = pos[row * 2] * W1[k] + pos[row * 2 + 1] * W1[64 + k];
        T1h[idx]  = (_Float16)v;
        T1bh[idx] = (_Float16)(v + b1[k]);
    }
}

// ---------------------------------------------------------------------------
// Prep kernel B: hp16[b*128+j][p] = hid[b,j,:] @ W2[0:128,p] + b2[p]  (f16)
// ---------------------------------------------------------------------------
__global__ void sp_hpart(const float* __restrict__ hs, const float* __restrict__ W2,
                         const float* __restrict__ b2, _Float16* __restrict__ hp16) {
    __shared__ float sh[8 * 128];
    int rb = blockIdx.x * 8;
    int tid = threadIdx.x;
    for (int t = tid; t < 1024; t += 256) sh[t] = hs[rb * 128 + t];
    __syncthreads();
    float acc[8];
    float bb = b2[tid];
#pragma unroll
    for (int r = 0; r < 8; ++r) acc[r] = bb;
    for (int k = 0; k < 128; ++k) {
        float w = W2[k * 256 + tid];
#pragma unroll
        for (int r = 0; r < 8; ++r) acc[r] += sh[r * 128 + k] * w;
    }
#pragma unroll
    for (int r = 0; r < 8; ++r) hp16[(rb + r) * 256 + tid] = (_Float16)acc[r];
}

// ---------------------------------------------------------------------------
// Main kernel: one block per (b, ph-half, i-group of 8) -> grid 512
// (2 blocks/CU). 4 waves; wave wj owns j in [32wj, 32wj+32).
//  TWO i PER ITERATION (the round-15 lever): each aw global load and each
//  bf ds_read feeds 4 MFMAs (2jt x 2i) instead of 2 -> per-i VMEM halves
//  (aw 32->16/i, ds_read 64->32/i), MFMA count unchanged.
//  Register budget (~244 unified = 116 arch + 128 AGPR eacc, r8 precedent):
//   - b1 folded into T1bh prep table (kills aprime regs + adds);
//   - h loads per-ks (ld_f16x4 x4/ks) instead of 32-persistent;
//   - w2p/hpp opaque passthroughs block LICM (r10's hoist-spill);
//   - full unrolls everywhere (static indices, rule #20).
// LDS: 64KB W3-half + 8KB pool = 72KB -> 2 blocks/CU.
// ---------------------------------------------------------------------------
__global__ __launch_bounds__(256, 2) void sp_main(
    const float* __restrict__ b3,
    const _Float16* __restrict__ hp16, const _Float16* __restrict__ W2bt,
    const _Float16* __restrict__ W3s, const _Float16* __restrict__ T1h,
    const _Float16* __restrict__ T1bh, float* __restrict__ pool) {
    __shared__ __align__(16) char sW3[8][8192];    // [ks][row'-local 128][64B]
    __shared__ _Float16 sPoolH[4][8][128];         // [wj][ii][p'-local]

    const int bid = blockIdx.x;
    const int ig = bid & 15, ph = (bid >> 4) & 1, b = bid >> 5;
    const int tid = threadIdx.x;
    const int wj = tid >> 6, lane = tid & 63;
    const int l15 = lane & 15, lk = lane >> 4;

    // --- stage W3 half (64KB): rows [ph*128, ph*128+128) of each ks chunk --
    {
        const uint4* W3v = (const uint4*)W3s + ph * 512;
        uint4* dst = (uint4*)sW3;
#pragma unroll
        for (int c = 0; c < 16; ++c) {
            dst[c * 256 + tid] = W3v[c * 256 + tid + (c >> 1) * 512];
        }
    }

    // --- tb[jt][s32] = T1bh[j] fragments (i-invariant, 16 regs, hoisted) ---
    f16x8 tb[2][2];
#pragma unroll
    for (int jt = 0; jt < 2; ++jt) {
        int j = wj * 32 + jt * 16 + l15;
        const _Float16* tj = T1bh + (b * 128 + j) * 64 + lk * 8;
        tb[jt][0] = ld_f16x8(tj);
        tb[jt][1] = ld_f16x8(tj + 32);
    }

    const _Float16* hpb = hp16 + (b * 128 + wj * 32 + l15) * 256 + lk * 4;
    const _Float16* tib = T1h + (b * 128) * 64 + lk * 8;   // + i*64 per iter
    const int slot = lk ^ ((l15 >> 1) & 3);   // read-side bank swizzle

    __syncthreads();   // sW3 ready

    // =================== barrier-free loop: 4 iters x 2 i ==================
#pragma unroll 1
    for (int ii2 = 0; ii2 < 4; ++ii2) {
        const int i0 = ig * 8 + ii2 * 2;
        const int i1 = i0 + 1;

        // Opaque passthroughs: block LICM from hoisting i-invariant loads
        // (aw: 128 regs if cached; h: 32 regs -> both = r10's spill).
        const _Float16* w2p = W2bt;
        const _Float16* hpp = hpb;
        asm volatile("" : "+v"(w2p), "+v"(hpp));

        // --- benc[iq][jt][s32] = relu(tb - T1[i])  (packed f16) ------------
        f16x8 benc[2][2][2];
#pragma unroll
        for (int iq = 0; iq < 2; ++iq) {
            const int i = iq ? i1 : i0;
#pragma unroll
            for (int s32 = 0; s32 < 2; ++s32) {
                f16x8 cv = ld_f16x8(tib + i * 64 + s32 * 32);
#pragma unroll
                for (int jt = 0; jt < 2; ++jt) {
                    f16x8 v;
#pragma unroll
                    for (int e = 0; e < 8; ++e) {
                        _Float16 d = tb[jt][s32][e] - cv[e];
                        v[e] = d > (_Float16)0 ? d : (_Float16)0;
                    }
                    benc[iq][jt][s32] = v;
                }
            }
        }

        f32x4 eacc[2][2][8];   // [iq][jt][pt] -> 128 AGPR
#pragma unroll
        for (int iq = 0; iq < 2; ++iq)
#pragma unroll
            for (int jt = 0; jt < 2; ++jt)
#pragma unroll
                for (int pt = 0; pt < 8; ++pt)
                    eacc[iq][jt][pt] = (f32x4){0.f, 0.f, 0.f, 0.f};

        // --- fused per-ks: GEMM1 (2 pt, 4-way shared aw) -> u jit ->
        //     GEMM2 (8 pt', 4-way shared bf) --------------------------------
#pragma unroll
        for (int ks = 0; ks < 8; ++ks) {
            f16x8 u[2][2];   // [iq][jt]
#pragma unroll
            for (int pp = 0; pp < 2; ++pp) {
                const int pt = ks * 2 + pp;
                f32x4 a[2][2];
#pragma unroll
                for (int iq = 0; iq < 2; ++iq)
#pragma unroll
                    for (int jt = 0; jt < 2; ++jt) a[iq][jt] = (f32x4){0.f, 0.f, 0.f, 0.f};
#pragma unroll
                for (int s32 = 0; s32 < 2; ++s32) {
                    f16x8 aw = ld_f16x8(w2p + (pt * 16 + l15) * 64 + s32 * 32 + lk * 8);
                    a[0][0] = __builtin_amdgcn_mfma_f32_16x16x32_f16(aw, benc[0][0][s32], a[0][0], 0, 0, 0);
                    a[0][1] = __builtin_amdgcn_mfma_f32_16x16x32_f16(aw, benc[0][1][s32], a[0][1], 0, 0, 0);
                    a[1][0] = __builtin_amdgcn_mfma_f32_16x16x32_f16(aw, benc[1][0][s32], a[1][0], 0, 0, 0);
                    a[1][1] = __builtin_amdgcn_mfma_f32_16x16x32_f16(aw, benc[1][1][s32], a[1][1], 0, 0, 0);
                }
                f16x4 h0 = ld_f16x4(hpp + pt * 16);
                f16x4 h1 = ld_f16x4(hpp + 16 * 256 + pt * 16);
#pragma unroll
                for (int iq = 0; iq < 2; ++iq)
#pragma unroll
                    for (int r = 0; r < 4; ++r) {
                        float t0 = a[iq][0][r] + (float)h0[r];
                        float t1 = a[iq][1][r] + (float)h1[r];
                        u[iq][0][pp * 4 + r] = (_Float16)(t0 > 0.f ? t0 : 0.f);
                        u[iq][1][pp * 4 + r] = (_Float16)(t1 > 0.f ? t1 : 0.f);
                    }
            }
#pragma unroll
            for (int pt = 0; pt < 8; ++pt) {
                f16x8 bf = ld_f16x8(sW3[ks] + (pt * 16 + l15) * 64 + slot * 16);
                eacc[0][0][pt] = __builtin_amdgcn_mfma_f32_16x16x32_f16(u[0][0], bf, eacc[0][0][pt], 0, 0, 0);
                eacc[0][1][pt] = __builtin_amdgcn_mfma_f32_16x16x32_f16(u[0][1], bf, eacc[0][1][pt], 0, 0, 0);
                eacc[1][0][pt] = __builtin_amdgcn_mfma_f32_16x16x32_f16(u[1][0], bf, eacc[1][0][pt], 0, 0, 0);
                eacc[1][1][pt] = __builtin_amdgcn_mfma_f32_16x16x32_f16(u[1][1], bf, eacc[1][1][pt], 0, 0, 0);
            }
        }

        // --- masked max over this wave's 32 j -> private sPoolH slices -----
        // eacc: row j = wj*32 + jt*16 + 4lk + r, col p' = ph*128 + pt*16 + l15
#pragma unroll
        for (int iq = 0; iq < 2; ++iq) {
            const int i = iq ? i1 : i0;
#pragma unroll
            for (int pt = 0; pt < 8; ++pt) {
                float m = -INFINITY;
#pragma unroll
                for (int jt = 0; jt < 2; ++jt) {
#pragma unroll
                    for (int r = 0; r < 4; ++r) {
                        int row = wj * 32 + jt * 16 + lk * 4 + r;
                        float v = eacc[iq][jt][pt][r];
                        if (row != i) m = fmaxf(m, v);
                    }
                }
                m = fmaxf(m, __shfl_xor(m, 16));
                m = fmaxf(m, __shfl_xor(m, 32));
                if (lane < 16) sPoolH[wj][ii2 * 2 + iq][pt * 16 + l15] = (_Float16)m;
            }
        }
    }
    __syncthreads();   // all waves' sPoolH complete

    // --- cross-wave max + b3 -> pooled rows (d_out, write-only) ------------
#pragma unroll
    for (int q = 0; q < 4; ++q) {
        int idx = q * 256 + tid;           // 0..1023 = 8 ii x 128 p'-local
        int ii = idx >> 7, t = idx & 127;
        float v = fmaxf(fmaxf((float)sPoolH[0][ii][t], (float)sPoolH[1][ii][t]),
                        fmaxf((float)sPoolH[2][ii][t], (float)sPoolH[3][ii][t]));
        int p = ph * 128 + t;
        pool[(b * 128 + ig * 8 + ii) * 256 + p] = v + b3[p];
    }
}

// ---------------------------------------------------------------------------
// Final: io = io @ Wout + bout, IN PLACE on d_out (8 rows per block; rows
// staged to LDS behind a barrier before any write -> in-place safe).
// ---------------------------------------------------------------------------
__global__ void sp_out(const float* __restrict__ Wout, const float* __restrict__ bout,
                       float* __restrict__ io) {
    __shared__ float sp[8 * 256];
    int rb = blockIdx.x * 8;
    int tid = threadIdx.x;
    for (int t = tid; t < 2048; t += 256) sp[t] = io[rb * 256 + t];
    __syncthreads();
    float acc[8];
    float bb = bout[tid];
#pragma unroll
    for (int r = 0; r < 8; ++r) acc[r] = bb;
    for (int k = 0; k < 256; ++k) {
        float w = Wout[k * 256 + tid];
#pragma unroll
        for (int r = 0; r < 8; ++r) acc[r] += sp[r * 256 + k] * w;
    }
#pragma unroll
    for (int r = 0; r < 8; ++r) io[(rb + r) * 256 + tid] = acc[r];
}

extern "C" void kernel_launch(void* const* d_in, const int* in_sizes, int n_in,
                              void* d_out, int out_size, void* d_ws, size_t ws_size,
                              hipStream_t stream) {
    const float* hs   = (const float*)d_in[0];
    const float* pos  = (const float*)d_in[1];
    const float* W1   = (const float*)d_in[2];
    const float* b1   = (const float*)d_in[3];
    const float* W2   = (const float*)d_in[4];
    const float* b2   = (const float*)d_in[5];
    const float* W3   = (const float*)d_in[6];
    const float* b3   = (const float*)d_in[7];
    const float* Wout = (const float*)d_in[8];
    const float* bout = (const float*)d_in[9];
    float* out = (float*)d_out;

    // ws: hp16 1MB | W2bt 32KB | W3s 128KB | T1h 256KB | T1bh 256KB (~1.7MB)
    _Float16* hp16 = (_Float16*)d_ws;
    _Float16* W2bt = (_Float16*)((char*)d_ws + (1 << 20));
    _Float16* W3s  = (_Float16*)((char*)d_ws + (1 << 20) + 32768);
    _Float16* T1h  = (_Float16*)((char*)d_ws + (1 << 20) + 32768 + 131072);
    _Float16* T1bh = (_Float16*)((char*)d_ws + (1 << 20) + 32768 + 131072 + 262144);

    sp_wconv<<<256, 256, 0, stream>>>(W2, W3, pos, W1, b1, W2bt, W3s, T1h, T1bh);
    sp_hpart<<<256, 256, 0, stream>>>(hs, W2, b2, hp16);
    sp_main<<<512, 256, 0, stream>>>(b3, hp16, W2bt, W3s, T1h, T1bh, out);
    sp_out<<<256, 256, 0, stream>>>(Wout, bout, out);
}

// Round 16
// 94.908 us; speedup vs baseline: 2.7226x; 1.0509x over previous
//
#include <hip/hip_runtime.h>
#include <hip/hip_fp16.h>

// Problem constants: B=16, N=128, H=128, BD=64, P=256
using f16x4 = __attribute__((ext_vector_type(4))) _Float16;
using f16x8 = __attribute__((ext_vector_type(8))) _Float16;
using f32x4 = __attribute__((ext_vector_type(4))) float;
using f32x16 = __attribute__((ext_vector_type(16))) float;

__device__ __forceinline__ f16x4 ld_f16x4(const void* p) {
    return *reinterpret_cast<const f16x4*>(p);
}
__device__ __forceinline__ f16x8 ld_f16x8(const void* p) {
    return *reinterpret_cast<const f16x8*>(p);
}

// ---------------------------------------------------------------------------
// 32x32x16 MFMA layout conventions (gfx950):
//  A[m][k]: m = lane&31, k-slot = (hi = lane>>5, e 0..7)
//  B[k][n]: n = lane&31, k-slot = (hi, e)
//  C/D    : col = lane&31, row = (reg&3) + 8*(reg>>2) + 4*hi   [m74/m101]
// k-slot physical labels are free as long as A and B agree (slot-consistent).
//
//  GEMM1 (transposed, M=p tile of 32, N=j 32): physical k = s*16 + hi*8 + e.
//   D gives p-local row = (r&3)+8*(r>>2)+4hi, j = lane&31.  Regs 0..7 are
//   exactly the K=16 A-frag for GEMM2 kstep 2t under
//   sigma(hi,e) = (e&3)+8*(e>>2)+4*hi; regs 8..15 -> kstep 2t+1.
//  GEMM2: A = u (M=j), B = W3s with slot sigma + bank swizzle.
//
// Prep kernel A: W2bt[p][k] = W2[128+k][p] (f16 plain transpose, 64/row).
//  W3s[kk][row p'][slot 0..1][e 0..7] = W3[k][row], k = kk*16 + (e&3) +
//    8*(e>>2) + 4*h, h = slot ^ ((row>>2)&1)  (bank swizzle folded in).
//  T1h [n][64] = pos[n]@W1; T1bh[n][64] = pos[n]@W1 + b1  (f16 tables).
// ---------------------------------------------------------------------------
__global__ void sp_wconv(const float* __restrict__ W2, const float* __restrict__ W3,
                         const float* __restrict__ pos, const float* __restrict__ W1,
                         const float* __restrict__ b1,
                         _Float16* __restrict__ W2bt, _Float16* __restrict__ W3s,
                         _Float16* __restrict__ T1h, _Float16* __restrict__ T1bh) {
    int t = blockIdx.x * 256 + threadIdx.x;   // grid covers 65536
    if (t < 16384) {
        int p = t >> 6, k = t & 63;
        W2bt[t] = (_Float16)W2[(128 + k) * 256 + p];
    }
    {
        // W3s: 16 kk x 256 rows x 16 f16 = 65536 elements
        int kk = t >> 12, rem = t & 4095;
        int row = rem >> 4, inner = rem & 15;
        int slot = inner >> 3, e = inner & 7;
        int h = slot ^ ((row >> 2) & 1);
        int k = kk * 16 + (e & 3) + 8 * (e >> 2) + 4 * h;
        W3s[t] = (_Float16)W3[k * 256 + row];
    }
#pragma unroll
    for (int h = 0; h < 2; ++h) {
        int idx = t + h * 65536;              // 131072 = 2048 rows x 64
        int row = idx >> 6, k = idx & 63;
        float v = pos[row * 2] * W1[k] + pos[row * 2 + 1] * W1[64 + k];
        T1h[idx]  = (_Float16)v;
        T1bh[idx] = (_Float16)(v + b1[k]);
    }
}

// ---------------------------------------------------------------------------
// Prep kernel B: hp16[b*128+j][p] = hid[b,j,:] @ W2[0:128,p] + b2[p]  (f16)
// ---------------------------------------------------------------------------
__global__ void sp_hpart(const float* __restrict__ hs, const float* __restrict__ W2,
                         const float* __restrict__ b2, _Float16* __restrict__ hp16) {
    __shared__ float sh[8 * 128];
    int rb = blockIdx.x * 8;
    int tid = threadIdx.x;
    for (int t = tid; t < 1024; t += 256) sh[t] = hs[rb * 128 + t];
    __syncthreads();
    float acc[8];
    float bb = b2[tid];
#pragma unroll
    for (int r = 0; r < 8; ++r) acc[r] = bb;
    for (int k = 0; k < 128; ++k) {
        float w = W2[k * 256 + tid];
#pragma unroll
        for (int r = 0; r < 8; ++r) acc[r] += sh[r * 128 + k] * w;
    }
#pragma unroll
    for (int r = 0; r < 8; ++r) hp16[(rb + r) * 256 + tid] = (_Float16)acc[r];
}

// ---------------------------------------------------------------------------
// Main kernel: one block per (b, ph-half, i-group of 8) -> grid 512
// (2 blocks/CU). 4 waves; wave wj owns j = wj*32 + (lane&31) (one j/lane).
//  32x32x16 MFMA: HALF the MFMA instructions of r15 at same FLOPs, same
//  VMEM counts; +2-i sharing (each aw/bf feeds 2 i).
//  Per iter (2 i): benc = relu(T1bh[j]-T1h[i]) -> per p-tile t (8):
//  { GEMM1 4 ksteps x 2iq -> u-pack from D regs (0..7 / 8..15) ->
//    GEMM2 ksteps 2t,2t+1 x 4 nt x 2iq from resident LDS } -> masked max.
// LDS: 64KB W3-half + 8KB pool = 72KB -> 2 blocks/CU.
// Regs ~110 arch + 128 AGPR eacc < 256 cap at (256,2).
// ---------------------------------------------------------------------------
__global__ __launch_bounds__(256, 2) void sp_main(
    const float* __restrict__ b3,
    const _Float16* __restrict__ hp16, const _Float16* __restrict__ W2bt,
    const _Float16* __restrict__ W3s, const _Float16* __restrict__ T1h,
    const _Float16* __restrict__ T1bh, float* __restrict__ pool) {
    __shared__ __align__(16) char sW3[16][4096];   // [kk][128 rows][32B]
    __shared__ _Float16 sPoolH[4][8][128];         // [wj][ii][p'-local]

    const int bid = blockIdx.x;
    const int ig = bid & 15, ph = (bid >> 4) & 1, b = bid >> 5;
    const int tid = threadIdx.x;
    const int wj = tid >> 6, lane = tid & 63;
    const int l31 = lane & 31, hi = lane >> 5;

    // --- stage W3 half (64KB): rows [ph*128, ph*128+128) of each kk --------
    {
        const uint4* W3v = (const uint4*)W3s;
        uint4* dst = (uint4*)sW3;
#pragma unroll
        for (int c = 0; c < 16; ++c)
            dst[c * 256 + tid] = W3v[c * 512 + ph * 256 + tid];
    }

    const int jl = wj * 32 + l31;                       // this lane's j
    const _Float16* tjb = T1bh + (b * 128 + jl) * 64 + hi * 8;
    const _Float16* tib = T1h + (b * 128) * 64 + hi * 8;   // + i*64 per iter
    const _Float16* hpb = hp16 + (b * 128 + jl) * 256;
    const int slotB = (hi ^ ((l31 >> 2) & 1)) * 16;     // bank-swizzled 16B half

    __syncthreads();   // sW3 ready

    // =================== barrier-free loop: 4 iters x 2 i ==================
#pragma unroll 1
    for (int ii2 = 0; ii2 < 4; ++ii2) {
        const int i0 = ig * 8 + ii2 * 2;
        const int i1 = i0 + 1;

        // Opaque passthroughs: block LICM from hoisting i-invariant loads
        // (aw = 64 regs, hp = 32 regs if cached -> r10's spill).
        const _Float16* w2p = W2bt;
        const _Float16* hpp = hpb;
        asm volatile("" : "+v"(w2p), "+v"(hpp));

        // --- benc[iq][s] = relu(T1bh[j] - T1h[i])  k = s*16 + hi*8 + e ------
        f16x8 benc[2][4];
#pragma unroll
        for (int s = 0; s < 4; ++s) {
            f16x8 tbv = ld_f16x8(tjb + s * 16);
            f16x8 cv0 = ld_f16x8(tib + i0 * 64 + s * 16);
            f16x8 cv1 = ld_f16x8(tib + i1 * 64 + s * 16);
#pragma unroll
            for (int e = 0; e < 8; ++e) {
                _Float16 d0 = tbv[e] - cv0[e];
                _Float16 d1 = tbv[e] - cv1[e];
                benc[0][s][e] = d0 > (_Float16)0 ? d0 : (_Float16)0;
                benc[1][s][e] = d1 > (_Float16)0 ? d1 : (_Float16)0;
            }
        }

        f32x16 eacc[2][4];   // [iq][nt] -> 128 AGPR
#pragma unroll
        for (int iq = 0; iq < 2; ++iq)
#pragma unroll
            for (int nt = 0; nt < 4; ++nt)
#pragma unroll
                for (int r = 0; r < 16; ++r) eacc[iq][nt][r] = 0.f;

        // --- per p-tile: GEMM1 -> u-pack -> GEMM2 (ksteps 2t, 2t+1) --------
#pragma unroll
        for (int t = 0; t < 8; ++t) {
            f32x16 a0, a1;
#pragma unroll
            for (int r = 0; r < 16; ++r) { a0[r] = 0.f; a1[r] = 0.f; }
#pragma unroll
            for (int s = 0; s < 4; ++s) {
                f16x8 aw = ld_f16x8(w2p + (t * 32 + l31) * 64 + s * 16 + hi * 8);
                a0 = __builtin_amdgcn_mfma_f32_32x32x16_f16(aw, benc[0][s], a0, 0, 0, 0);
                a1 = __builtin_amdgcn_mfma_f32_32x32x16_f16(aw, benc[1][s], a1, 0, 0, 0);
            }
            // hp for this lane's j at p = t*32 + {0,8,16,24} + 4hi (+0..3)
            f16x4 hp0 = ld_f16x4(hpp + t * 32 + 4 * hi);
            f16x4 hp1 = ld_f16x4(hpp + t * 32 + 8 + 4 * hi);
            f16x4 hp2 = ld_f16x4(hpp + t * 32 + 16 + 4 * hi);
            f16x4 hp3 = ld_f16x4(hpp + t * 32 + 24 + 4 * hi);
            // u-pack: regs 0..7 -> kstep 2t frag; regs 8..15 -> kstep 2t+1
            f16x8 u00, u01, u10, u11;   // u{kstephalf}{...}: u0x=iq0, u1x=iq1
#pragma unroll
            for (int e = 0; e < 4; ++e) {
                _Float16 v;
                v = (_Float16)a0[e]      + hp0[e]; u00[e]     = v > (_Float16)0 ? v : (_Float16)0;
                v = (_Float16)a0[e + 4]  + hp1[e]; u00[e + 4] = v > (_Float16)0 ? v : (_Float16)0;
                v = (_Float16)a0[e + 8]  + hp2[e]; u01[e]     = v > (_Float16)0 ? v : (_Float16)0;
                v = (_Float16)a0[e + 12] + hp3[e]; u01[e + 4] = v > (_Float16)0 ? v : (_Float16)0;
                v = (_Float16)a1[e]      + hp0[e]; u10[e]     = v > (_Float16)0 ? v : (_Float16)0;
                v = (_Float16)a1[e + 4]  + hp1[e]; u10[e + 4] = v > (_Float16)0 ? v : (_Float16)0;
                v = (_Float16)a1[e + 8]  + hp2[e]; u11[e]     = v > (_Float16)0 ? v : (_Float16)0;
                v = (_Float16)a1[e + 12] + hp3[e]; u11[e + 4] = v > (_Float16)0 ? v : (_Float16)0;
            }
#pragma unroll
            for (int nt = 0; nt < 4; ++nt) {
                const char* rowp = (const char*)sW3 + (nt * 32 + l31) * 32 + slotB;
                f16x8 bf0 = ld_f16x8(rowp + (2 * t) * 4096);
                f16x8 bf1 = ld_f16x8(rowp + (2 * t + 1) * 4096);
                eacc[0][nt] = __builtin_amdgcn_mfma_f32_32x32x16_f16(u00, bf0, eacc[0][nt], 0, 0, 0);
                eacc[1][nt] = __builtin_amdgcn_mfma_f32_32x32x16_f16(u10, bf0, eacc[1][nt], 0, 0, 0);
                eacc[0][nt] = __builtin_amdgcn_mfma_f32_32x32x16_f16(u01, bf1, eacc[0][nt], 0, 0, 0);
                eacc[1][nt] = __builtin_amdgcn_mfma_f32_32x32x16_f16(u11, bf1, eacc[1][nt], 0, 0, 0);
            }
        }

        // --- masked max over 32 j -> sPoolH ---------------------------------
        // eacc: row j = wj*32 + (r&3)+8*(r>>2)+4hi, col p' = ph*128+nt*32+l31
#pragma unroll
        for (int iq = 0; iq < 2; ++iq) {
            const int i = iq ? i1 : i0;
#pragma unroll
            for (int nt = 0; nt < 4; ++nt) {
                float m = -INFINITY;
#pragma unroll
                for (int r = 0; r < 16; ++r) {
                    int jrow = wj * 32 + (r & 3) + 8 * (r >> 2) + 4 * hi;
                    float v = eacc[iq][nt][r];
                    if (jrow != i) m = fmaxf(m, v);
                }
                m = fmaxf(m, __shfl_xor(m, 32));   // combine hi halves
                if (lane < 32) sPoolH[wj][ii2 * 2 + iq][nt * 32 + l31] = (_Float16)m;
            }
        }
    }
    __syncthreads();   // all waves' sPoolH complete

    // --- cross-wave max + b3 -> pooled rows (d_out, write-only) ------------
#pragma unroll
    for (int q = 0; q < 4; ++q) {
        int idx = q * 256 + tid;           // 0..1023 = 8 ii x 128 p'-local
        int ii = idx >> 7, t = idx & 127;
        float v = fmaxf(fmaxf((float)sPoolH[0][ii][t], (float)sPoolH[1][ii][t]),
                        fmaxf((float)sPoolH[2][ii][t], (float)sPoolH[3][ii][t]));
        int p = ph * 128 + t;
        pool[(b * 128 + ig * 8 + ii) * 256 + p] = v + b3[p];
    }
}

// ---------------------------------------------------------------------------
// Final: io = io @ Wout + bout, IN PLACE on d_out (8 rows per block; rows
// staged to LDS behind a barrier before any write -> in-place safe).
// ---------------------------------------------------------------------------
__global__ void sp_out(const float* __restrict__ Wout, const float* __restrict__ bout,
                       float* __restrict__ io) {
    __shared__ float sp[8 * 256];
    int rb = blockIdx.x * 8;
    int tid = threadIdx.x;
    for (int t = tid; t < 2048; t += 256) sp[t] = io[rb * 256 + t];
    __syncthreads();
    float acc[8];
    float bb = bout[tid];
#pragma unroll
    for (int r = 0; r < 8; ++r) acc[r] = bb;
    for (int k = 0; k < 256; ++k) {
        float w = Wout[k * 256 + tid];
#pragma unroll
        for (int r = 0; r < 8; ++r) acc[r] += sp[r * 256 + k] * w;
    }
#pragma unroll
    for (int r = 0; r < 8; ++r) io[(rb + r) * 256 + tid] = acc[r];
}

extern "C" void kernel_launch(void* const* d_in, const int* in_sizes, int n_in,
                              void* d_out, int out_size, void* d_ws, size_t ws_size,
                              hipStream_t stream) {
    const float* hs   = (const float*)d_in[0];
    const float* pos  = (const float*)d_in[1];
    const float* W1   = (const float*)d_in[2];
    const float* b1   = (const float*)d_in[3];
    const float* W2   = (const float*)d_in[4];
    const float* b2   = (const float*)d_in[5];
    const float* W3   = (const float*)d_in[6];
    const float* b3   = (const float*)d_in[7];
    const float* Wout = (const float*)d_in[8];
    const float* bout = (const float*)d_in[9];
    float* out = (float*)d_out;

    // ws: hp16 1MB | W2bt 32KB | W3s 128KB | T1h 256KB | T1bh 256KB (~1.7MB)
    _Float16* hp16 = (_Float16*)d_ws;
    _Float16* W2bt = (_Float16*)((char*)d_ws + (1 << 20));
    _Float16* W3s  = (_Float16*)((char*)d_ws + (1 << 20) + 32768);
    _Float16* T1h  = (_Float16*)((char*)d_ws + (1 << 20) + 32768 + 131072);
    _Float16* T1bh = (_Float16*)((char*)d_ws + (1 << 20) + 32768 + 131072 + 262144);

    sp_wconv<<<256, 256, 0, stream>>>(W2, W3, pos, W1, b1, W2bt, W3s, T1h, T1bh);
    sp_hpart<<<256, 256, 0, stream>>>(hs, W2, b2, hp16);
    sp_main<<<512, 256, 0, stream>>>(b3, hp16, W2bt, W3s, T1h, T1bh, out);
    sp_out<<<256, 256, 0, stream>>>(Wout, bout, out);
}